// Round 1
// baseline (1212.161 us; speedup 1.0000x reference)
//
#include <hip/hip_runtime.h>
#include <math.h>

#define Bn 8
#define Cn 112
#define Hn 64
#define Wn 64
#define On 112
#define Gn 14
#define K2n 9
#define PGC 378          // 3*G*K2
#define HW 4096          // 64*64
#define CKW 1008         // C*K2 (inner dim of main conv)

// ---------------------------------------------------------------------------
// Kernel 1: pg = conv3x3(x, pg_weight, pad=1) + pg_bias
// block = 256 threads, 32x32 spatial tile, 9 output channels, 4 px/thread
// grid  = (2, 2, 8*42)
// ---------------------------------------------------------------------------
__global__ __launch_bounds__(256) void pg_conv_kernel(
    const float* __restrict__ x, const float* __restrict__ pgw,
    const float* __restrict__ pgb, float* __restrict__ pg)
{
    __shared__ __align__(16) float xt[34 * 34];
    __shared__ float wt[81];

    const int tid = threadIdx.x;
    const int b   = blockIdx.z / 42;
    const int oc0 = (blockIdx.z % 42) * 9;
    const int ty0 = blockIdx.y * 32, tx0 = blockIdx.x * 32;
    const int rx = tid & 31;        // col within tile
    const int ry = tid >> 5;        // row group 0..7 (4 rows each)

    float acc[4][9];
    #pragma unroll
    for (int q = 0; q < 4; ++q)
        #pragma unroll
        for (int j = 0; j < 9; ++j)
            acc[q][j] = pgb[oc0 + j];

    const float* xb = x + (size_t)b * Cn * HW;

    for (int c = 0; c < Cn; ++c) {
        // stage 34x34 halo tile of x[b,c]
        const float* xc = xb + (size_t)c * HW;
        for (int i = tid; i < 34 * 34; i += 256) {
            int r = i / 34, cl = i % 34;
            int yy = ty0 + r - 1, xx = tx0 + cl - 1;
            float v = 0.f;
            if (yy >= 0 && yy < Hn && xx >= 0 && xx < Wn) v = xc[yy * Wn + xx];
            xt[i] = v;
        }
        // stage 9 oc x 9 tap weights
        if (tid < 81)
            wt[tid] = pgw[(size_t)(oc0 + tid / 9) * CKW + c * 9 + (tid % 9)];
        __syncthreads();

        for (int k = 0; k < 9; ++k) {
            const int ky = k / 3, kx = k % 3;
            float wr[9];
            #pragma unroll
            for (int j = 0; j < 9; ++j) wr[j] = wt[j * 9 + k];
            #pragma unroll
            for (int q = 0; q < 4; ++q) {
                float xv = xt[(ry * 4 + q + ky) * 34 + rx + kx];
                #pragma unroll
                for (int j = 0; j < 9; ++j)
                    acc[q][j] = fmaf(xv, wr[j], acc[q][j]);
            }
        }
        __syncthreads();
    }

    #pragma unroll
    for (int q = 0; q < 4; ++q) {
        int ho = ty0 + ry * 4 + q, wo = tx0 + rx;
        float* po = pg + (size_t)b * PGC * HW + ho * Wn + wo;
        #pragma unroll
        for (int j = 0; j < 9; ++j)
            po[(size_t)(oc0 + j) * HW] = acc[q][j];
    }
}

// ---------------------------------------------------------------------------
// Kernel 2: fused deformable sampling + main conv
// block = 256 threads, one (batch, 8x8 pixel tile); loops over 14 groups.
//   phase A: sampled chunk (8ch x 9k x 64px) -> LDS, weight slab (112x72) -> LDS
//   phase B: per-thread 28 output channels x 1 pixel register GEMM
// grid = (64, 8)
// ---------------------------------------------------------------------------
__global__ __launch_bounds__(256) void deform_kernel(
    const float* __restrict__ x, const float* __restrict__ pg,
    const float* __restrict__ w, const float* __restrict__ bias,
    float* __restrict__ out)
{
    __shared__ __align__(16) float smp[64][76];   // [px][cc*9+k], pad 76
    __shared__ __align__(16) float wt[112 * 72];  // [o][ck]

    const int tid  = threadIdx.x;
    const int b    = blockIdx.y;
    const int tile = blockIdx.x;
    const int th0 = (tile >> 3) * 8, tw0 = (tile & 7) * 8;
    const int px = tid & 63;
    const int obase = (tid >> 6) * 28;     // 4 groups x 28 = 112
    const int ho = th0 + (px >> 3), wo = tw0 + (px & 7);

    float acc[28];
    #pragma unroll
    for (int j = 0; j < 28; ++j) acc[j] = 0.f;

    const float* pgb_ = pg + (size_t)b * PGC * HW;
    const float* xb   = x + (size_t)b * Cn * HW;

    for (int g = 0; g < Gn; ++g) {
        // stage weight slab: wt[o][ck] = w[o*1008 + g*72 + ck]
        for (int i = tid; i < 112 * 72; i += 256) {
            int o = i / 72, ck = i % 72;
            wt[i] = w[(size_t)o * CKW + g * 72 + ck];
        }
        // compute sampled values for this group
        for (int loc = tid; loc < 576; loc += 256) {
            int p = loc / 9, k = loc % 9;
            int hh = th0 + (p >> 3), ww = tw0 + (p & 7);
            int pos = hh * Wn + ww;
            float dy = pgb_[(size_t)(18 * g + 2 * k) * HW + pos];
            float dx = pgb_[(size_t)(18 * g + 2 * k + 1) * HW + pos];
            float mv = pgb_[(size_t)(252 + 9 * g + k) * HW + pos];
            float m  = 1.f / (1.f + expf(-mv));

            float yf = (float)(hh - 1 + k / 3) + dy;
            float xf = (float)(ww - 1 + k % 3) + dx;
            float y0 = floorf(yf), x0 = floorf(xf);
            float wy1 = yf - y0, wx1 = xf - x0;
            float wy0 = 1.f - wy1, wx0 = 1.f - wx1;
            int iy0 = (int)y0, ix0 = (int)x0;
            bool vy0 = (iy0 >= 0) && (iy0 <= Hn - 1);
            bool vy1 = (iy0 + 1 >= 0) && (iy0 + 1 <= Hn - 1);
            bool vx0 = (ix0 >= 0) && (ix0 <= Wn - 1);
            bool vx1 = (ix0 + 1 >= 0) && (ix0 + 1 <= Wn - 1);
            int cy0 = min(max(iy0, 0), Hn - 1), cy1 = min(max(iy0 + 1, 0), Hn - 1);
            int cx0 = min(max(ix0, 0), Wn - 1), cx1 = min(max(ix0 + 1, 0), Wn - 1);
            float w00 = (vy0 && vx0) ? wy0 * wx0 * m : 0.f;
            float w01 = (vy0 && vx1) ? wy0 * wx1 * m : 0.f;
            float w10 = (vy1 && vx0) ? wy1 * wx0 * m : 0.f;
            float w11 = (vy1 && vx1) ? wy1 * wx1 * m : 0.f;
            int i00 = cy0 * Wn + cx0, i01 = cy0 * Wn + cx1;
            int i10 = cy1 * Wn + cx0, i11 = cy1 * Wn + cx1;
            const float* xg = xb + (size_t)(g * 8) * HW;
            #pragma unroll
            for (int cc = 0; cc < 8; ++cc) {
                const float* img = xg + (size_t)cc * HW;
                float v = img[i00] * w00 + img[i01] * w01 +
                          img[i10] * w10 + img[i11] * w11;
                smp[p][cc * 9 + k] = v;
            }
        }
        __syncthreads();

        // register GEMM: acc[j] += smp[px][ck] * wt[obase+j][ck]
        for (int c4 = 0; c4 < 18; ++c4) {
            float4 s4 = *reinterpret_cast<const float4*>(&smp[px][c4 * 4]);
            #pragma unroll
            for (int j = 0; j < 28; ++j) {
                float4 w4 = *reinterpret_cast<const float4*>(&wt[(obase + j) * 72 + c4 * 4]);
                acc[j] = fmaf(s4.x, w4.x, acc[j]);
                acc[j] = fmaf(s4.y, w4.y, acc[j]);
                acc[j] = fmaf(s4.z, w4.z, acc[j]);
                acc[j] = fmaf(s4.w, w4.w, acc[j]);
            }
        }
        __syncthreads();
    }

    float* ob = out + (size_t)b * On * HW + ho * Wn + wo;
    #pragma unroll
    for (int j = 0; j < 28; ++j) {
        int o = obase + j;
        ob[(size_t)o * HW] = acc[j] + bias[o];
    }
}

// ---------------------------------------------------------------------------
extern "C" void kernel_launch(void* const* d_in, const int* in_sizes, int n_in,
                              void* d_out, int out_size, void* d_ws, size_t ws_size,
                              hipStream_t stream) {
    const float* x    = (const float*)d_in[0];
    const float* pgw  = (const float*)d_in[1];
    const float* pgb  = (const float*)d_in[2];
    const float* w    = (const float*)d_in[3];
    const float* bias = (const float*)d_in[4];
    float* out = (float*)d_out;
    float* pg  = (float*)d_ws;   // 8*378*4096*4 = 49.5 MB

    dim3 g1(2, 2, Bn * 42);
    pg_conv_kernel<<<g1, 256, 0, stream>>>(x, pgw, pgb, pg);

    dim3 g2(64, Bn);
    deform_kernel<<<g2, 256, 0, stream>>>(x, pg, w, bias, out);
}

// Round 2
// 425.536 us; speedup vs baseline: 2.8486x; 2.8486x over previous
//
#include <hip/hip_runtime.h>
#include <math.h>

#define Bn 8
#define Cn 112
#define Hn 64
#define Wn 64
#define On 112
#define Gn 14
#define PGC 378          // 3*G*K2
#define HW 4096          // 64*64
#define CKW 1008         // C*K2 (inner dim)
#define KP 1024          // padded K for GEMM
#define NP 384           // padded N (oc) for GEMM
#define MHALF 16384      // half-batch pixel count (4*4096)

typedef __attribute__((ext_vector_type(8))) short bf16x8;
typedef __attribute__((ext_vector_type(4))) float f32x4;

__device__ __forceinline__ unsigned short f2bf(float f) {
    union { float f; unsigned int u; } v; v.f = f;
    unsigned int r = v.u + 0x7fffu + ((v.u >> 16) & 1u);
    return (unsigned short)(r >> 16);
}
__device__ __forceinline__ float bf2f(unsigned short u) {
    union { unsigned int u; float f; } v; v.u = ((unsigned int)u) << 16;
    return v.f;
}
__device__ __forceinline__ void gload_lds16(const void* g, void* l) {
    __builtin_amdgcn_global_load_lds(
        (const __attribute__((address_space(1))) unsigned int*)g,
        (__attribute__((address_space(3))) unsigned int*)l, 16, 0, 0);
}

// ---------------------------------------------------------------------------
// Kernel: im2col (half batch) -> A2 bf16 [16384][1024], zero-padded K tail
// ---------------------------------------------------------------------------
__global__ __launch_bounds__(256) void im2col_kernel(
    const float* __restrict__ x, unsigned short* __restrict__ A2, int half)
{
    int t = blockIdx.x * 256 + threadIdx.x;   // 16384*128 threads
    int pxl = t >> 7;
    int ck0 = (t & 127) << 3;
    int pxg = half * MHALF + pxl;
    int b = pxg >> 12, hw = pxg & 4095;
    int h = hw >> 6, ww = hw & 63;
    const float* xb = x + (size_t)b * Cn * HW;

    unsigned short o[8];
    #pragma unroll
    for (int j = 0; j < 8; ++j) {
        int ck = ck0 + j;
        float v = 0.f;
        if (ck < CKW) {
            int c = ck / 9, k = ck - 9 * c;
            int yy = h + k / 3 - 1, xx = ww + (k % 3) - 1;
            if (yy >= 0 && yy < Hn && xx >= 0 && xx < Wn)
                v = xb[c * HW + yy * Wn + xx];
        }
        o[j] = f2bf(v);
    }
    *reinterpret_cast<uint4*>(&A2[(size_t)pxl * KP + ck0]) =
        *reinterpret_cast<const uint4*>(o);
}

// ---------------------------------------------------------------------------
// Kernel: prep B2 bf16 [384][1024] from pg_weight (zero-padded)
// ---------------------------------------------------------------------------
__global__ __launch_bounds__(256) void prep_b_kernel(
    const float* __restrict__ pgw, unsigned short* __restrict__ B2)
{
    int t = blockIdx.x * 256 + threadIdx.x;   // 384*1024
    int oc = t >> 10, ck = t & 1023;
    float v = (oc < PGC && ck < CKW) ? pgw[(size_t)oc * CKW + ck] : 0.f;
    B2[t] = f2bf(v);
}

// ---------------------------------------------------------------------------
// Kernel: pg GEMM  C[px][oc] = A2[px][k] * B2[oc][k] + pgb[oc]
// 128x128 tile, BK=32, 4 waves (2x2), mfma_f32_16x16x32_bf16
// writes pg bf16 in [b][oc][hw] layout
// ---------------------------------------------------------------------------
__global__ __launch_bounds__(256) void pg_gemm_kernel(
    const unsigned short* __restrict__ A2, const unsigned short* __restrict__ B2,
    const float* __restrict__ pgb, unsigned short* __restrict__ pgBF, int half)
{
    __shared__ __align__(16) unsigned short Asm[128 * 32];
    __shared__ __align__(16) unsigned short Bsm[128 * 32];

    const int tid  = threadIdx.x;
    const int lane = tid & 63;
    const int w    = tid >> 6;
    const int wr   = w >> 1, wc = w & 1;
    const int m0   = blockIdx.x * 128;   // px_local base
    const int n0   = blockIdx.y * 128;   // oc base
    const int fr   = lane & 15, fq = lane >> 4;

    f32x4 acc[4][4] = {};

    const int ldr = lane >> 2;            // row within 16-row chunk
    const int ldc = (lane & 3) * 8;       // ushort col offset (16B)

    for (int kt = 0; kt < 32; ++kt) {
        if (kt) __syncthreads();
        // stage A,B tiles: wave w covers rows [w*32, w*32+32)
        #pragma unroll
        for (int i = 0; i < 2; ++i) {
            int row = w * 32 + i * 16 + ldr;
            gload_lds16(&A2[(size_t)(m0 + row) * KP + kt * 32 + ldc],
                        &Asm[(w * 32 + i * 16) * 32]);
            gload_lds16(&B2[(size_t)(n0 + row) * KP + kt * 32 + ldc],
                        &Bsm[(w * 32 + i * 16) * 32]);
        }
        __syncthreads();

        bf16x8 a[4], b[4];
        #pragma unroll
        for (int mi = 0; mi < 4; ++mi)
            a[mi] = *reinterpret_cast<const bf16x8*>(
                &Asm[(wr * 64 + mi * 16 + fr) * 32 + fq * 8]);
        #pragma unroll
        for (int ni = 0; ni < 4; ++ni)
            b[ni] = *reinterpret_cast<const bf16x8*>(
                &Bsm[(wc * 64 + ni * 16 + fr) * 32 + fq * 8]);
        #pragma unroll
        for (int mi = 0; mi < 4; ++mi)
            #pragma unroll
            for (int ni = 0; ni < 4; ++ni)
                acc[mi][ni] = __builtin_amdgcn_mfma_f32_16x16x32_bf16(
                    a[mi], b[ni], acc[mi][ni], 0, 0, 0);
    }

    // epilogue: add bias, convert bf16, scatter to pg[b][oc][hw]
    #pragma unroll
    for (int ni = 0; ni < 4; ++ni) {
        int oc = n0 + wc * 64 + ni * 16 + fr;
        if (oc >= PGC) continue;
        float bias = pgb[oc];
        #pragma unroll
        for (int mi = 0; mi < 4; ++mi) {
            int pxl = m0 + wr * 64 + mi * 16 + fq * 4;
            int pxg = half * MHALF + pxl;
            int b = pxg >> 12, hw = pxg & 4095;
            ushort4 pk;
            pk.x = f2bf(acc[mi][ni][0] + bias);
            pk.y = f2bf(acc[mi][ni][1] + bias);
            pk.z = f2bf(acc[mi][ni][2] + bias);
            pk.w = f2bf(acc[mi][ni][3] + bias);
            *reinterpret_cast<ushort4*>(
                &pgBF[((size_t)(b * PGC + oc)) * HW + hw]) = pk;
        }
    }
}

// ---------------------------------------------------------------------------
// Kernel: fused deformable sampling + main conv (unchanged except bf16 pg)
// ---------------------------------------------------------------------------
__global__ __launch_bounds__(256) void deform_kernel(
    const float* __restrict__ x, const unsigned short* __restrict__ pg,
    const float* __restrict__ w, const float* __restrict__ bias,
    float* __restrict__ out)
{
    __shared__ __align__(16) float smp[64][76];
    __shared__ __align__(16) float wt[112 * 72];

    const int tid  = threadIdx.x;
    const int b    = blockIdx.y;
    const int tile = blockIdx.x;
    const int th0 = (tile >> 3) * 8, tw0 = (tile & 7) * 8;
    const int px = tid & 63;
    const int obase = (tid >> 6) * 28;
    const int ho = th0 + (px >> 3), wo = tw0 + (px & 7);

    float acc[28];
    #pragma unroll
    for (int j = 0; j < 28; ++j) acc[j] = 0.f;

    const unsigned short* pgb_ = pg + (size_t)b * PGC * HW;
    const float* xb = x + (size_t)b * Cn * HW;

    for (int g = 0; g < Gn; ++g) {
        for (int i = tid; i < 112 * 72; i += 256) {
            int o = i / 72, ck = i % 72;
            wt[i] = w[(size_t)o * CKW + g * 72 + ck];
        }
        for (int loc = tid; loc < 576; loc += 256) {
            int p = loc / 9, k = loc % 9;
            int hh = th0 + (p >> 3), ww = tw0 + (p & 7);
            int pos = hh * Wn + ww;
            float dy = bf2f(pgb_[(size_t)(18 * g + 2 * k) * HW + pos]);
            float dx = bf2f(pgb_[(size_t)(18 * g + 2 * k + 1) * HW + pos]);
            float mv = bf2f(pgb_[(size_t)(252 + 9 * g + k) * HW + pos]);
            float m  = 1.f / (1.f + expf(-mv));

            float yf = (float)(hh - 1 + k / 3) + dy;
            float xf = (float)(ww - 1 + k % 3) + dx;
            float y0 = floorf(yf), x0 = floorf(xf);
            float wy1 = yf - y0, wx1 = xf - x0;
            float wy0 = 1.f - wy1, wx0 = 1.f - wx1;
            int iy0 = (int)y0, ix0 = (int)x0;
            bool vy0 = (iy0 >= 0) && (iy0 <= Hn - 1);
            bool vy1 = (iy0 + 1 >= 0) && (iy0 + 1 <= Hn - 1);
            bool vx0 = (ix0 >= 0) && (ix0 <= Wn - 1);
            bool vx1 = (ix0 + 1 >= 0) && (ix0 + 1 <= Wn - 1);
            int cy0 = min(max(iy0, 0), Hn - 1), cy1 = min(max(iy0 + 1, 0), Hn - 1);
            int cx0 = min(max(ix0, 0), Wn - 1), cx1 = min(max(ix0 + 1, 0), Wn - 1);
            float w00 = (vy0 && vx0) ? wy0 * wx0 * m : 0.f;
            float w01 = (vy0 && vx1) ? wy0 * wx1 * m : 0.f;
            float w10 = (vy1 && vx0) ? wy1 * wx0 * m : 0.f;
            float w11 = (vy1 && vx1) ? wy1 * wx1 * m : 0.f;
            int i00 = cy0 * Wn + cx0, i01 = cy0 * Wn + cx1;
            int i10 = cy1 * Wn + cx0, i11 = cy1 * Wn + cx1;
            const float* xg = xb + (size_t)(g * 8) * HW;
            #pragma unroll
            for (int cc = 0; cc < 8; ++cc) {
                const float* img = xg + (size_t)cc * HW;
                float v = img[i00] * w00 + img[i01] * w01 +
                          img[i10] * w10 + img[i11] * w11;
                smp[p][cc * 9 + k] = v;
            }
        }
        __syncthreads();

        for (int c4 = 0; c4 < 18; ++c4) {
            float4 s4 = *reinterpret_cast<const float4*>(&smp[px][c4 * 4]);
            #pragma unroll
            for (int j = 0; j < 28; ++j) {
                float4 w4 = *reinterpret_cast<const float4*>(&wt[(obase + j) * 72 + c4 * 4]);
                acc[j] = fmaf(s4.x, w4.x, acc[j]);
                acc[j] = fmaf(s4.y, w4.y, acc[j]);
                acc[j] = fmaf(s4.z, w4.z, acc[j]);
                acc[j] = fmaf(s4.w, w4.w, acc[j]);
            }
        }
        __syncthreads();
    }

    float* ob = out + (size_t)b * On * HW + ho * Wn + wo;
    #pragma unroll
    for (int j = 0; j < 28; ++j) {
        int o = obase + j;
        ob[(size_t)o * HW] = acc[j] + bias[o];
    }
}

// ---------------------------------------------------------------------------
extern "C" void kernel_launch(void* const* d_in, const int* in_sizes, int n_in,
                              void* d_out, int out_size, void* d_ws, size_t ws_size,
                              hipStream_t stream) {
    const float* x    = (const float*)d_in[0];
    const float* pgw  = (const float*)d_in[1];
    const float* pgb  = (const float*)d_in[2];
    const float* w    = (const float*)d_in[3];
    const float* bias = (const float*)d_in[4];
    float* out = (float*)d_out;

    char* wsb = (char*)d_ws;
    unsigned short* pgBF = (unsigned short*)wsb;                    // 24.77 MB
    unsigned short* B2   = (unsigned short*)(wsb + (size_t)PGC * Bn * HW * 2);
    unsigned short* A2   = (unsigned short*)(wsb + (size_t)PGC * Bn * HW * 2
                                                 + (size_t)NP * KP * 2);   // 33.55 MB

    prep_b_kernel<<<NP * KP / 256, 256, 0, stream>>>(pgw, B2);

    for (int half = 0; half < 2; ++half) {
        im2col_kernel<<<MHALF * 128 / 256, 256, 0, stream>>>(x, A2, half);
        dim3 gg(MHALF / 128, NP / 128);
        pg_gemm_kernel<<<gg, 256, 0, stream>>>(A2, B2, pgb, pgBF, half);
    }

    dim3 g2(64, Bn);
    deform_kernel<<<g2, 256, 0, stream>>>(x, pgBF, w, bias, out);
}

// Round 3
// 242.622 us; speedup vs baseline: 4.9961x; 1.7539x over previous
//
#include <hip/hip_runtime.h>
#include <math.h>

#define Bn 8
#define Cn 112
#define Hn 64
#define Wn 64
#define On 112
#define Gn 14
#define PGC 378          // 3*G*K2
#define HW 4096          // 64*64
#define CKW 1008         // C*K2 (inner dim)
#define KP 1024          // padded K for pg GEMM
#define NP 384           // padded N (oc) for pg GEMM
#define MHALF 16384      // half-batch pixel count
#define WKP 96           // padded per-group K in deform (k*8+cc, k<12)
#define WROW 192         // bytes per LDS row (96 bf16)

typedef __attribute__((ext_vector_type(8))) short bf16x8;
typedef __attribute__((ext_vector_type(4))) float f32x4;

__device__ __forceinline__ unsigned short f2bf(float f) {
    union { float f; unsigned int u; } v; v.f = f;
    unsigned int r = v.u + 0x7fffu + ((v.u >> 16) & 1u);
    return (unsigned short)(r >> 16);
}
__device__ __forceinline__ float bf2f(unsigned short u) {
    union { unsigned int u; float f; } v; v.u = ((unsigned int)u) << 16;
    return v.f;
}
__device__ __forceinline__ void gload_lds16(const void* g, void* l) {
    __builtin_amdgcn_global_load_lds(
        (const __attribute__((address_space(1))) unsigned int*)g,
        (__attribute__((address_space(3))) unsigned int*)l, 16, 0, 0);
}

// ---------------------------------------------------------------------------
// im2col (half batch) -> A2 bf16 [16384][1024]
// ---------------------------------------------------------------------------
__global__ __launch_bounds__(256) void im2col_kernel(
    const float* __restrict__ x, unsigned short* __restrict__ A2, int half)
{
    int t = blockIdx.x * 256 + threadIdx.x;
    int pxl = t >> 7;
    int ck0 = (t & 127) << 3;
    int pxg = half * MHALF + pxl;
    int b = pxg >> 12, hw = pxg & 4095;
    int h = hw >> 6, ww = hw & 63;
    const float* xb = x + (size_t)b * Cn * HW;

    unsigned short o[8];
    #pragma unroll
    for (int j = 0; j < 8; ++j) {
        int ck = ck0 + j;
        float v = 0.f;
        if (ck < CKW) {
            int c = ck / 9, k = ck - 9 * c;
            int yy = h + k / 3 - 1, xx = ww + (k % 3) - 1;
            if (yy >= 0 && yy < Hn && xx >= 0 && xx < Wn)
                v = xb[c * HW + yy * Wn + xx];
        }
        o[j] = f2bf(v);
    }
    *reinterpret_cast<uint4*>(&A2[(size_t)pxl * KP + ck0]) =
        *reinterpret_cast<const uint4*>(o);
}

// ---------------------------------------------------------------------------
// prep B2 bf16 [384][1024] from pg_weight
// ---------------------------------------------------------------------------
__global__ __launch_bounds__(256) void prep_b_kernel(
    const float* __restrict__ pgw, unsigned short* __restrict__ B2)
{
    int t = blockIdx.x * 256 + threadIdx.x;
    int oc = t >> 10, ck = t & 1023;
    float v = (oc < PGC && ck < CKW) ? pgw[(size_t)oc * CKW + ck] : 0.f;
    B2[t] = f2bf(v);
}

// ---------------------------------------------------------------------------
// prep wbfS: main-conv weights, bf16, layout [g][oc][k*8+cc] padded to 96,
// PRE-SWIZZLED in 16B chunks: chunk c = l ^ ((l/12)&7), l = oc*12 + (ck>>3),
// so deform can stage with linear global_load_lds and read with
// byte = (oc*192 + k*2) ^ ((oc&7)<<4).
// ---------------------------------------------------------------------------
__global__ __launch_bounds__(256) void prep_w_kernel(
    const float* __restrict__ w, unsigned short* __restrict__ wbfS)
{
    int t = blockIdx.x * 256 + threadIdx.x;   // 14*112*96 = 150528
    int g = t / 10752, r = t % 10752;
    int oc = r / 96, ck = r % 96;
    int k = ck >> 3, cc = ck & 7;
    float v = (k < 9) ? w[(size_t)oc * CKW + (g * 8 + cc) * 9 + k] : 0.f;
    int l = oc * 12 + (ck >> 3);
    int c = l ^ (oc & 7);
    wbfS[(size_t)g * 10752 + c * 8 + (ck & 7)] = f2bf(v);
}

// ---------------------------------------------------------------------------
// pg GEMM (unchanged from round 2, validated)
// ---------------------------------------------------------------------------
__global__ __launch_bounds__(256) void pg_gemm_kernel(
    const unsigned short* __restrict__ A2, const unsigned short* __restrict__ B2,
    const float* __restrict__ pgb, unsigned short* __restrict__ pgBF, int half)
{
    __shared__ __align__(16) unsigned short Asm[128 * 32];
    __shared__ __align__(16) unsigned short Bsm[128 * 32];

    const int tid  = threadIdx.x;
    const int lane = tid & 63;
    const int w    = tid >> 6;
    const int wr   = w >> 1, wc = w & 1;
    const int m0   = blockIdx.x * 128;
    const int n0   = blockIdx.y * 128;
    const int fr   = lane & 15, fq = lane >> 4;

    f32x4 acc[4][4] = {};

    const int ldr = lane >> 2;
    const int ldc = (lane & 3) * 8;

    for (int kt = 0; kt < 32; ++kt) {
        if (kt) __syncthreads();
        #pragma unroll
        for (int i = 0; i < 2; ++i) {
            int row = w * 32 + i * 16 + ldr;
            gload_lds16(&A2[(size_t)(m0 + row) * KP + kt * 32 + ldc],
                        &Asm[(w * 32 + i * 16) * 32]);
            gload_lds16(&B2[(size_t)(n0 + row) * KP + kt * 32 + ldc],
                        &Bsm[(w * 32 + i * 16) * 32]);
        }
        __syncthreads();

        bf16x8 a[4], b[4];
        #pragma unroll
        for (int mi = 0; mi < 4; ++mi)
            a[mi] = *reinterpret_cast<const bf16x8*>(
                &Asm[(wr * 64 + mi * 16 + fr) * 32 + fq * 8]);
        #pragma unroll
        for (int ni = 0; ni < 4; ++ni)
            b[ni] = *reinterpret_cast<const bf16x8*>(
                &Bsm[(wc * 64 + ni * 16 + fr) * 32 + fq * 8]);
        #pragma unroll
        for (int mi = 0; mi < 4; ++mi)
            #pragma unroll
            for (int ni = 0; ni < 4; ++ni)
                acc[mi][ni] = __builtin_amdgcn_mfma_f32_16x16x32_bf16(
                    a[mi], b[ni], acc[mi][ni], 0, 0, 0);
    }

    #pragma unroll
    for (int ni = 0; ni < 4; ++ni) {
        int oc = n0 + wc * 64 + ni * 16 + fr;
        if (oc >= PGC) continue;
        float bias = pgb[oc];
        #pragma unroll
        for (int mi = 0; mi < 4; ++mi) {
            int pxl = m0 + wr * 64 + mi * 16 + fq * 4;
            int pxg = half * MHALF + pxl;
            int b = pxg >> 12, hw = pxg & 4095;
            ushort4 pk;
            pk.x = f2bf(acc[mi][ni][0] + bias);
            pk.y = f2bf(acc[mi][ni][1] + bias);
            pk.z = f2bf(acc[mi][ni][2] + bias);
            pk.w = f2bf(acc[mi][ni][3] + bias);
            *reinterpret_cast<ushort4*>(
                &pgBF[((size_t)(b * PGC + oc)) * HW + hw]) = pk;
        }
    }
}

// ---------------------------------------------------------------------------
// deform: block = (batch b, image row y), 64 px, 4 waves.
// Per group g: stage wt (global_load_lds, pre-swizzled), sample 9 taps
// (lane = pixel -> coalesced gathers) into swizzled LDS, then MFMA GEMM:
// wave w owns px-tile [w*16, w*16+16), 7 oc-tiles, K = 96 (3 chunks).
// ---------------------------------------------------------------------------
__global__ __launch_bounds__(256) void deform_kernel(
    const float* __restrict__ x, const unsigned short* __restrict__ pg,
    const unsigned short* __restrict__ wbfS, const float* __restrict__ bias,
    float* __restrict__ out)
{
    __shared__ __align__(16) unsigned short wt[Cn * WKP];    // 21504 B
    __shared__ __align__(16) unsigned short smp[64 * WKP];   // 12288 B

    const int tid  = threadIdx.x;
    const int lane = tid & 63;
    const int w    = tid >> 6;
    const int y    = blockIdx.x;
    const int b    = blockIdx.y;

    // zero the pad taps (k=9..11) once; never overwritten afterwards
    if (tid < 64) {
        const uint4 z = {0, 0, 0, 0};
        #pragma unroll
        for (int k = 9; k < 12; ++k) {
            int byte = (tid * WROW + k * 16) ^ ((tid & 7) << 4);
            *reinterpret_cast<uint4*>(reinterpret_cast<char*>(smp) + byte) = z;
        }
    }

    f32x4 acc[7] = {};

    const unsigned short* pgb = pg + (size_t)b * PGC * HW + y * 64;
    const float* xb = x + (size_t)b * Cn * HW;

    for (int g = 0; g < Gn; ++g) {
        // stage weights: 21 x (64 lanes x 16B) linear global_load_lds
        {
            const char* src = (const char*)wbfS + (size_t)g * (Cn * WKP * 2);
            for (int wi = w; wi < 21; wi += 4)
                gload_lds16(src + (size_t)(wi * 64 + lane) * 16,
                            (char*)wt + wi * 1024);
        }
        // sample: tasks (k, px), lane = px -> coalesced pg reads + x gathers
        for (int t = tid; t < 576; t += 256) {
            const int k  = t >> 6;
            const int px = t & 63;
            const int ky = k / 3, kx = k % 3;
            float dy = bf2f(pgb[(size_t)(18 * g + 2 * k) * HW + px]);
            float dx = bf2f(pgb[(size_t)(18 * g + 2 * k + 1) * HW + px]);
            float mv = bf2f(pgb[(size_t)(252 + 9 * g + k) * HW + px]);
            float m  = 1.f / (1.f + __expf(-mv));

            float yf = (float)(y + ky - 1) + dy;
            float xf = (float)(px + kx - 1) + dx;
            float y0 = floorf(yf), x0 = floorf(xf);
            float wy1 = yf - y0, wx1 = xf - x0;
            float wy0 = 1.f - wy1, wx0 = 1.f - wx1;
            int iy0 = (int)y0, ix0 = (int)x0;
            bool vy0 = (iy0 >= 0) && (iy0 < Hn);
            bool vy1 = (iy0 >= -1) && (iy0 < Hn - 1);
            bool vx0 = (ix0 >= 0) && (ix0 < Wn);
            bool vx1 = (ix0 >= -1) && (ix0 < Wn - 1);
            int cy0 = min(max(iy0, 0), Hn - 1), cy1 = min(max(iy0 + 1, 0), Hn - 1);
            int cx0 = min(max(ix0, 0), Wn - 1), cx1 = min(max(ix0 + 1, 0), Wn - 1);
            float w00 = (vy0 && vx0) ? wy0 * wx0 * m : 0.f;
            float w01 = (vy0 && vx1) ? wy0 * wx1 * m : 0.f;
            float w10 = (vy1 && vx0) ? wy1 * wx0 * m : 0.f;
            float w11 = (vy1 && vx1) ? wy1 * wx1 * m : 0.f;
            int i00 = cy0 * Wn + cx0, i01 = cy0 * Wn + cx1;
            int i10 = cy1 * Wn + cx0, i11 = cy1 * Wn + cx1;
            const float* xg = xb + (size_t)(g * 8) * HW;

            unsigned int pk[4];
            #pragma unroll
            for (int c2 = 0; c2 < 4; ++c2) {
                const float* img0 = xg + (size_t)(2 * c2) * HW;
                const float* img1 = img0 + HW;
                float v0 = img0[i00] * w00 + img0[i01] * w01 +
                           img0[i10] * w10 + img0[i11] * w11;
                float v1 = img1[i00] * w00 + img1[i01] * w01 +
                           img1[i10] * w10 + img1[i11] * w11;
                pk[c2] = (unsigned int)f2bf(v0) | ((unsigned int)f2bf(v1) << 16);
            }
            int byte = (px * WROW + k * 16) ^ ((px & 7) << 4);
            *reinterpret_cast<uint4*>(reinterpret_cast<char*>(smp) + byte) =
                *reinterpret_cast<const uint4*>(pk);
        }
        __syncthreads();

        // MFMA GEMM
        const int pxl = w * 16 + (lane & 15);
        const int ocl = lane & 15;
        #pragma unroll
        for (int ch = 0; ch < 3; ++ch) {
            const int k0 = ch * 32 + (lane >> 4) * 8;
            int bbyte = (pxl * WROW + k0 * 2) ^ ((pxl & 7) << 4);
            bf16x8 bfrag = *reinterpret_cast<const bf16x8*>(
                reinterpret_cast<const char*>(smp) + bbyte);
            #pragma unroll
            for (int t2 = 0; t2 < 7; ++t2) {
                int oc = t2 * 16 + ocl;
                int abyte = (oc * WROW + k0 * 2) ^ ((oc & 7) << 4);
                bf16x8 afrag = *reinterpret_cast<const bf16x8*>(
                    reinterpret_cast<const char*>(wt) + abyte);
                acc[t2] = __builtin_amdgcn_mfma_f32_16x16x32_bf16(
                    afrag, bfrag, acc[t2], 0, 0, 0);
            }
        }
        __syncthreads();
    }

    const int pxl = w * 16 + (lane & 15);
    float* ob = out + (size_t)b * On * HW + y * 64 + pxl;
    #pragma unroll
    for (int t2 = 0; t2 < 7; ++t2) {
        #pragma unroll
        for (int r = 0; r < 4; ++r) {
            int oc = t2 * 16 + (lane >> 4) * 4 + r;
            ob[(size_t)oc * HW] = acc[t2][r] + bias[oc];
        }
    }
}

// ---------------------------------------------------------------------------
extern "C" void kernel_launch(void* const* d_in, const int* in_sizes, int n_in,
                              void* d_out, int out_size, void* d_ws, size_t ws_size,
                              hipStream_t stream) {
    const float* x    = (const float*)d_in[0];
    const float* pgw  = (const float*)d_in[1];
    const float* pgb  = (const float*)d_in[2];
    const float* w    = (const float*)d_in[3];
    const float* bias = (const float*)d_in[4];
    float* out = (float*)d_out;

    char* wsb = (char*)d_ws;
    unsigned short* pgBF = (unsigned short*)wsb;                       // 24.77 MB
    size_t off = (size_t)PGC * Bn * HW * 2;
    unsigned short* B2   = (unsigned short*)(wsb + off);               // 0.79 MB
    off += (size_t)NP * KP * 2;
    unsigned short* A2   = (unsigned short*)(wsb + off);               // 33.55 MB
    off += (size_t)MHALF * KP * 2;
    unsigned short* wbfS = (unsigned short*)(wsb + off);               // 0.30 MB

    prep_b_kernel<<<NP * KP / 256, 256, 0, stream>>>(pgw, B2);
    prep_w_kernel<<<(Gn * Cn * WKP) / 256, 256, 0, stream>>>(w, wbfS);

    for (int half = 0; half < 2; ++half) {
        im2col_kernel<<<MHALF * 128 / 256, 256, 0, stream>>>(x, A2, half);
        dim3 gg(MHALF / 128, NP / 128);
        pg_gemm_kernel<<<gg, 256, 0, stream>>>(A2, B2, pgb, pgBF, half);
    }

    dim3 gD(Hn, Bn);
    deform_kernel<<<gD, 256, 0, stream>>>(x, pgBF, wbfS, bias, out);
}